// Round 1
// baseline (72.559 us; speedup 1.0000x reference)
//
#include <hip/hip_runtime.h>
#include <math.h>

#define EPS_T 1e-4f
#define BIG 1e10f
#define NRM_EPS 1e-12f

constexpr int MAX_S = 128;
constexpr int MAX_L = 64;

__global__ __launch_bounds__(256) void illum_kernel(
    const float* __restrict__ ray_o,
    const float* __restrict__ ray_d,
    const float* __restrict__ centers,
    const float* __restrict__ radii,
    const float* __restrict__ light_pos,
    const int*   __restrict__ light_idx,
    float* __restrict__ out,   // [N*3] results, then [N] active(0/1)
    int N, int S, int L)
{
    __shared__ float4 sph[MAX_S];   // x,y,z = center, w = |c|^2 - r^2
    __shared__ float  lps[MAX_L * 3];

    const int tid = threadIdx.x;
    if (tid < S) {
        float cx = centers[3 * tid + 0];
        float cy = centers[3 * tid + 1];
        float cz = centers[3 * tid + 2];
        float r  = radii[tid];
        sph[tid] = make_float4(cx, cy, cz, cx * cx + cy * cy + cz * cz - r * r);
    }
    if (tid < L * 3) lps[tid] = light_pos[tid];
    __syncthreads();

    const int i = blockIdx.x * blockDim.x + tid;
    if (i >= N) return;

    float ox = ray_o[3 * i + 0], oy = ray_o[3 * i + 1], oz = ray_o[3 * i + 2];
    float dx = ray_d[3 * i + 0], dy = ray_d[3 * i + 1], dz = ray_d[3 * i + 2];

    // d = normalize(ray_d) with eps per reference (x / max(||x||, 1e-12))
    float dn  = sqrtf(dx * dx + dy * dy + dz * dz);
    float din = 1.0f / fmaxf(dn, NRM_EPS);
    dx *= din; dy *= din; dz *= din;

    const float od = ox * dx + oy * dy + oz * dz;
    const float oo = ox * ox + oy * oy + oz * oz;

    float tmin = BIG;
    int   sidx = 0;
    #pragma unroll 4
    for (int s = 0; s < S; ++s) {
        float4 cs = sph[s];
        float doc = dx * cs.x + dy * cs.y + dz * cs.z;
        float ooc = ox * cs.x + oy * cs.y + oz * cs.z;
        float b   = od - doc;
        float c   = oo - 2.0f * ooc + cs.w;
        float disc = b * b - c;
        float t = -b - sqrtf(fmaxf(disc, 0.0f));
        bool valid = (disc > 0.0f) && (t > EPS_T);
        t = valid ? t : BIG;
        if (t < tmin) { tmin = t; sidx = s; }   // strict < keeps first index (jnp.argmin)
    }

    const bool active = (tmin < BIG);

    // hit point
    float px = fmaf(tmin, dx, ox);
    float py = fmaf(tmin, dy, oy);
    float pz = fmaf(tmin, dz, oz);

    // surface normal
    float4 cb = sph[sidx];
    float nx = px - cb.x, ny = py - cb.y, nz = pz - cb.z;
    float nn  = sqrtf(nx * nx + ny * ny + nz * nz);
    float nin = 1.0f / fmaxf(nn, NRM_EPS);
    nx *= nin; ny *= nin; nz *= nin;

    // direction to sampled light
    int li = light_idx[i];
    float dsx = lps[3 * li + 0] - px;
    float dsy = lps[3 * li + 1] - py;
    float dsz = lps[3 * li + 2] - pz;

    // Duff et al. branchless orthonormal frame; local = (d.s, d.t, d.n)
    float sgn = (nz >= 0.0f) ? 1.0f : -1.0f;
    float a   = -1.0f / (sgn + nz);
    float bb  = nx * ny * a;
    float sx = 1.0f + sgn * nx * nx * a, sy = sgn * bb,          sz = -sgn * nx;
    float tx = bb,                       ty = sgn + ny * ny * a, tz = -ny;

    float l0 = dsx * sx + dsy * sy + dsz * sz;
    float l1 = dsx * tx + dsy * ty + dsz * tz;
    float l2 = dsx * nx + dsy * ny + dsz * nz;
    float ln  = sqrtf(l0 * l0 + l1 * l1 + l2 * l2);
    float lin = 1.0f / fmaxf(ln, NRM_EPS);

    float r0 = active ? (l0 * lin + 1.0f) * 0.5f : 0.0f;
    float r1 = active ? (l1 * lin + 1.0f) * 0.5f : 0.0f;
    float r2 = active ? (l2 * lin + 1.0f) * 0.5f : 0.0f;

    out[3 * i + 0] = (1.0f + r0) * 0.5f;
    out[3 * i + 1] = (1.0f + r1) * 0.5f;
    out[3 * i + 2] = (1.0f + r2) * 0.5f;
    out[(size_t)3 * N + i] = active ? 1.0f : 0.0f;
}

extern "C" void kernel_launch(void* const* d_in, const int* in_sizes, int n_in,
                              void* d_out, int out_size, void* d_ws, size_t ws_size,
                              hipStream_t stream) {
    const float* ray_o     = (const float*)d_in[0];
    const float* ray_d     = (const float*)d_in[1];
    const float* centers   = (const float*)d_in[2];
    const float* radii     = (const float*)d_in[3];
    const float* light_pos = (const float*)d_in[4];
    const int*   light_idx = (const int*)d_in[5];
    float* out = (float*)d_out;

    const int N = in_sizes[0] / 3;
    const int S = in_sizes[3];
    const int L = in_sizes[4] / 3;

    const int block = 256;
    const int grid  = (N + block - 1) / block;
    illum_kernel<<<grid, block, 0, stream>>>(ray_o, ray_d, centers, radii,
                                             light_pos, light_idx, out, N, S, L);
}

// Round 2
// 36.050 us; speedup vs baseline: 2.0127x; 2.0127x over previous
//
#include <hip/hip_runtime.h>
#include <math.h>

#define EPS_T 1e-4f
#define BIG 1e10f
#define NRM_EPS 1e-12f

typedef float v2f __attribute__((ext_vector_type(2)));

constexpr int MAX_SP = 64;   // sphere pairs (S=128)
constexpr int MAX_L  = 64;

__global__ __launch_bounds__(256) void illum_kernel(
    const float* __restrict__ ray_o,
    const float* __restrict__ ray_d,
    const float* __restrict__ centers,
    const float* __restrict__ radii,
    const float* __restrict__ light_pos,
    const int*   __restrict__ light_idx,
    float* __restrict__ out,   // [N*3] results, then [N] active(0/1)
    int N, int S, int L)
{
    // pair-SoA sphere layout: sAB = (x0,x1,y0,y1), sZW = (z0,z1,w0,w1), w=|c|^2-r^2
    __shared__ float4 sAB[MAX_SP];
    __shared__ float4 sZW[MAX_SP];
    __shared__ float  lps[MAX_L * 3];

    const int tid = threadIdx.x;
    const int SP = S >> 1;
    if (tid < SP) {
        float x0 = centers[6 * tid + 0], y0 = centers[6 * tid + 1], z0 = centers[6 * tid + 2];
        float x1 = centers[6 * tid + 3], y1 = centers[6 * tid + 4], z1 = centers[6 * tid + 5];
        float r0 = radii[2 * tid + 0],   r1 = radii[2 * tid + 1];
        float w0 = x0 * x0 + y0 * y0 + z0 * z0 - r0 * r0;
        float w1 = x1 * x1 + y1 * y1 + z1 * z1 - r1 * r1;
        sAB[tid] = make_float4(x0, x1, y0, y1);
        sZW[tid] = make_float4(z0, z1, w0, w1);
    }
    if (tid < 3 * L) lps[tid] = light_pos[tid];
    __syncthreads();

    const int i = blockIdx.x * blockDim.x + tid;
    if (i >= N) return;

    float ox = ray_o[3 * i + 0], oy = ray_o[3 * i + 1], oz = ray_o[3 * i + 2];
    float dx = ray_d[3 * i + 0], dy = ray_d[3 * i + 1], dz = ray_d[3 * i + 2];

    // d = normalize(ray_d), precise (once per ray; matches reference rounding class)
    float dn  = sqrtf(dx * dx + dy * dy + dz * dz);
    float din = 1.0f / fmaxf(dn, NRM_EPS);
    dx *= din; dy *= din; dz *= din;

    const float od = ox * dx + oy * dy + oz * dz;
    const float oo = ox * ox + oy * oy + oz * oz;

    float tmin = BIG;
    int   sidx = 0;

    #pragma unroll 8
    for (int j = 0; j < SP; ++j) {
        float4 ab = sAB[j];
        float4 zw = sZW[j];
        v2f cx = {ab.x, ab.y};
        v2f cy = {ab.z, ab.w};
        v2f cz = {zw.x, zw.y};
        v2f cw = {zw.z, zw.w};

        // packed dual-sphere quadratic (v_pk_fma_f32 path)
        v2f doc = dx * cx + dy * cy + dz * cz;   // d . c
        v2f ooc = ox * cx + oy * cy + oz * cz;   // o . c
        v2f bm  = doc - od;                       // -b  (exact negation of ref's b)
        v2f cv  = oo - 2.0f * ooc + cw;           // same contraction form as passed kernel
        v2f dsc = bm * bm - cv;                   // disc (bm^2 == b^2 exactly)

        // raw v_sqrt_f32 (1 ulp); disc<0 -> NaN, filtered by disc>0 compare below
        float sq0 = __builtin_amdgcn_sqrtf(dsc.x);
        float sq1 = __builtin_amdgcn_sqrtf(dsc.y);
        float t0  = bm.x - sq0;                   // t = -b - sqrt(disc)
        float t1  = bm.y - sq1;

        // sequential, strict-< selection preserves jnp.argmin first-min tie-break
        bool c0 = (dsc.x > 0.0f) & (t0 > EPS_T) & (t0 < tmin);
        tmin = c0 ? t0 : tmin;
        sidx = c0 ? (2 * j + 0) : sidx;
        bool c1 = (dsc.y > 0.0f) & (t1 > EPS_T) & (t1 < tmin);
        tmin = c1 ? t1 : tmin;
        sidx = c1 ? (2 * j + 1) : sidx;
    }

    const bool active = (tmin < BIG);

    // hit point
    float px = fmaf(tmin, dx, ox);
    float py = fmaf(tmin, dy, oy);
    float pz = fmaf(tmin, dz, oz);

    // surface normal (precise epilogue, amortized)
    float4 ab = sAB[sidx >> 1];
    float4 zw = sZW[sidx >> 1];
    float cbx = (sidx & 1) ? ab.y : ab.x;
    float cby = (sidx & 1) ? ab.w : ab.z;
    float cbz = (sidx & 1) ? zw.y : zw.x;
    float nx = px - cbx, ny = py - cby, nz = pz - cbz;
    float nn  = sqrtf(nx * nx + ny * ny + nz * nz);
    float nin = 1.0f / fmaxf(nn, NRM_EPS);
    nx *= nin; ny *= nin; nz *= nin;

    // direction to sampled light
    int li = light_idx[i];
    float dsx = lps[3 * li + 0] - px;
    float dsy = lps[3 * li + 1] - py;
    float dsz = lps[3 * li + 2] - pz;

    // Duff et al. branchless orthonormal frame; local = (d.s, d.t, d.n)
    float sgn = (nz >= 0.0f) ? 1.0f : -1.0f;
    float a   = -1.0f / (sgn + nz);
    float bb  = nx * ny * a;
    float sx = 1.0f + sgn * nx * nx * a, sy = sgn * bb,          sz = -sgn * nx;
    float tx = bb,                       ty = sgn + ny * ny * a, tz = -ny;

    float l0 = dsx * sx + dsy * sy + dsz * sz;
    float l1 = dsx * tx + dsy * ty + dsz * tz;
    float l2 = dsx * nx + dsy * ny + dsz * nz;
    float ln  = sqrtf(l0 * l0 + l1 * l1 + l2 * l2);
    float lin = 1.0f / fmaxf(ln, NRM_EPS);

    float r0 = active ? (l0 * lin + 1.0f) * 0.5f : 0.0f;
    float r1 = active ? (l1 * lin + 1.0f) * 0.5f : 0.0f;
    float r2 = active ? (l2 * lin + 1.0f) * 0.5f : 0.0f;

    out[3 * i + 0] = (1.0f + r0) * 0.5f;
    out[3 * i + 1] = (1.0f + r1) * 0.5f;
    out[3 * i + 2] = (1.0f + r2) * 0.5f;
    out[(size_t)3 * N + i] = active ? 1.0f : 0.0f;
}

extern "C" void kernel_launch(void* const* d_in, const int* in_sizes, int n_in,
                              void* d_out, int out_size, void* d_ws, size_t ws_size,
                              hipStream_t stream) {
    const float* ray_o     = (const float*)d_in[0];
    const float* ray_d     = (const float*)d_in[1];
    const float* centers   = (const float*)d_in[2];
    const float* radii     = (const float*)d_in[3];
    const float* light_pos = (const float*)d_in[4];
    const int*   light_idx = (const int*)d_in[5];
    float* out = (float*)d_out;

    const int N = in_sizes[0] / 3;
    const int S = in_sizes[3];
    const int L = in_sizes[4] / 3;

    const int block = 256;
    const int grid  = (N + block - 1) / block;
    illum_kernel<<<grid, block, 0, stream>>>(ray_o, ray_d, centers, radii,
                                             light_pos, light_idx, out, N, S, L);
}